// Round 16
// baseline (407.631 us; speedup 1.0000x reference)
//
#include <hip/hip_runtime.h>
#include <math.h>
#include <stdint.h>

#define ND 128
#define NNB 32
#define NH 8

typedef __attribute__((ext_vector_type(8))) short bf16x8;
typedef __attribute__((ext_vector_type(4))) float f32x4;
typedef __attribute__((ext_vector_type(8))) unsigned short u16x8;
typedef __attribute__((ext_vector_type(2))) unsigned int u32x2;
typedef unsigned short u16;
typedef unsigned int u32;
typedef unsigned long long u64;

// ---- ws layout (bytes); all weights transposed Wt[N][K] bf16, LINEAR ----
#define OFF_QW1T 0ULL
#define OFF_QW2T 32768ULL
#define OFF_GW1T 294912ULL     // [128][32] (K padded 12->32 with zeros)
#define OFF_GW2T 303104ULL
#define OFF_KW1T 335872ULL
#define OFF_KW2T 368640ULL
#define OFF_VW1T 401408ULL
#define OFF_VW2T 434176ULL
#define OFF_DW1T 466944ULL     // [128][1024]
#define OFF_DW2T 729088ULL
#define OFF_Q    761856ULL     // [20096][1024] bf16, linear
#define OFF_ATT  (OFF_Q + 20096ULL * 2048ULL)  // chunk-swizzled by (pid&7)

// soft barrier: drain LDS ops only (NOT vmcnt) then barrier.
#define SBAR() asm volatile("s_waitcnt lgkmcnt(0)\n\ts_barrier" ::: "memory")

__device__ __forceinline__ u16 rneb(float f){
    u32 u = __builtin_bit_cast(u32, f);
    u32 r = u + 0x7fffu + ((u >> 16) & 1u);
    return (u16)(r >> 16);
}
__device__ __forceinline__ float elu_f(float v){ return v > 0.f ? v : (__expf(v) - 1.f); }

__device__ __forceinline__ u32 cvtpk(float a, float b){
    u32 r;
    asm("v_cvt_pk_bf16_f32 %0, %1, %2" : "=v"(r) : "v"(a), "v"(b));
    return r;
}
__device__ __forceinline__ u32x2 cvt4(float a, float b, float c, float d){
    u32x2 r; r.x = cvtpk(a, b); r.y = cvtpk(c, d); return r;
}

// async global->LDS, 16B per lane (linear dest)
#define GLDS16(g, l) __builtin_amdgcn_global_load_lds( \
    (const __attribute__((address_space(1))) u32*)(g), \
    (__attribute__((address_space(3))) u32*)(u32)(u64)(l), 16, 0, 0)

// fragment read from LDS: row-major [*][128] bf16 (256B rows), byte ^= (r&7)<<4
__device__ __forceinline__ bf16x8 ldfrag(const u16* base, int row, int kb, int l){
    int r = row + (l & 15);
    int byte = (r << 8) + (((kb << 1) + ((l >> 4) << 4)) ^ ((r & 7) << 4));
    return *(const bf16x8*)((const char*)base + byte);
}
// 64B-row variant (RL tile [128][32]), byte ^= (r&3)<<4
__device__ __forceinline__ bf16x8 ldfragRL(const u16* base, int row, int l){
    int r = row + (l & 15);
    int byte = (r << 6) + ((((l >> 4) << 4)) ^ ((r & 3) << 4));
    return *(const bf16x8*)((const char*)base + byte);
}
// fragment directly from global Wt[N][K] (linear, row stride kstride bytes)
__device__ __forceinline__ bf16x8 ldfragG(const char* __restrict__ Wt, int n, int kstride, int kb, int l){
    return *(const bf16x8*)(Wt + (size_t)(n + (l & 15)) * (size_t)kstride
                               + (size_t)((kb << 1) + ((l >> 4) << 4)));
}

// gemm over one row-half (64 rows) with REGISTER-RESIDENT weights.
// wave tile: 32 out-ch (m0) x 64 rows. 16 ds_reads, 32 MFMA.
__device__ __forceinline__ void gemm_half(const bf16x8 aw[4][2], const u16* B,
                                          int nbase, f32x4 acc[2][4], int l){
    __builtin_amdgcn_s_setprio(1);
    #pragma unroll
    for (int kk = 0; kk < 4; kk++){
        #pragma unroll
        for (int nt = 0; nt < 4; nt++){
            bf16x8 b = ldfrag(B, nbase + nt * 16, kk * 32, l);
            acc[0][nt] = __builtin_amdgcn_mfma_f32_16x16x32_bf16(aw[kk][0], b, acc[0][nt], 0, 0, 0);
            acc[1][nt] = __builtin_amdgcn_mfma_f32_16x16x32_bf16(aw[kk][1], b, acc[1][nt], 0, 0, 0);
        }
    }
    __builtin_amdgcn_s_setprio(0);
}

__device__ __forceinline__ void bias_init2(f32x4 acc[2][4], const float* __restrict__ bias,
                                           int m0, int hi){
    #pragma unroll
    for (int mt = 0; mt < 2; mt++){
        float4 bq = *(const float4*)&bias[m0 + mt * 16 + (hi << 2)];
        #pragma unroll
        for (int nt = 0; nt < 4; nt++)
            acc[mt][nt] = (f32x4){bq.x, bq.y, bq.z, bq.w};
    }
}

// full layer, register-weights: ACT 0 linear, 1 elu, 2 linear*dis*F_nn
template<int ACT, bool INPLACE>
__device__ __forceinline__ void layerP(
    const u16* inB, u16* outB, const bf16x8 aw[4][2],
    const float* __restrict__ bias, const float* __restrict__ F,
    const int* sidx, const float* sdis, int m0, int l, int hi)
{
    #pragma unroll
    for (int half = 0; half < 2; half++){
        const int nbase = half * 64;
        float4 fv[2][4]; float ds[4];
        if (ACT == 2){
            #pragma unroll
            for (int nt = 0; nt < 4; nt++){
                int row = nbase + nt * 16 + (l & 15);
                int ix = sidx[row];
                ds[nt] = sdis[row];
                fv[0][nt] = *(const float4*)&F[(size_t)ix * ND + m0 + (hi << 2)];
                fv[1][nt] = *(const float4*)&F[(size_t)ix * ND + m0 + 16 + (hi << 2)];
            }
        }
        f32x4 acc[2][4];
        bias_init2(acc, bias, m0, hi);
        gemm_half(aw, inB, nbase, acc, l);
        if (INPLACE) SBAR();   // all waves' reads of this half done before writes
        #pragma unroll
        for (int mt = 0; mt < 2; mt++){
            int ch0 = m0 + mt * 16 + (hi << 2);
            #pragma unroll
            for (int nt = 0; nt < 4; nt++){
                int row = nbase + nt * 16 + (l & 15);
                float v0 = acc[mt][nt][0], v1 = acc[mt][nt][1];
                float v2 = acc[mt][nt][2], v3 = acc[mt][nt][3];
                if (ACT == 1){ v0 = elu_f(v0); v1 = elu_f(v1); v2 = elu_f(v2); v3 = elu_f(v3); }
                if (ACT == 2){
                    float s = ds[nt];
                    v0 *= s * fv[mt][nt].x; v1 *= s * fv[mt][nt].y;
                    v2 *= s * fv[mt][nt].z; v3 *= s * fv[mt][nt].w;
                }
                *(u32x2*)((char*)outB + (row << 8) + (((ch0 << 1)) ^ ((row & 7) << 4))) =
                    cvt4(v0, v1, v2, v3);
            }
        }
    }
    SBAR();
}

// ---------------------------------------------------------------------------
// prep: W (Ksrc x N f32) -> Wt (N x Kdst bf16, zero-padded), linear
// ---------------------------------------------------------------------------
struct PrepDesc {
    const float* src[10];
    u64 dstoff[10];
    int N[10], Ksrc[10], Kdst[10];
};

__global__ __launch_bounds__(256) void prep_weights(PrepDesc d, char* ws){
    int tid = blockIdx.x * 256 + threadIdx.x;
    #pragma unroll 1
    for (int m = 0; m < 10; m++){
        int cnt = (d.Kdst[m] * d.N[m]) >> 3;
        if (tid < cnt){
            int N = d.N[m];
            int nn = tid % N, k8 = tid / N;
            const float* s = d.src[m];
            u16x8 pk;
            #pragma unroll
            for (int i = 0; i < 8; i++){
                int k = k8 * 8 + i;
                pk[i] = (k < d.Ksrc[m]) ? rneb(s[(size_t)k * N + nn]) : (u16)0;
            }
            *(u16x8*)(ws + d.dstoff[m] + (u64)nn * (u64)(d.Kdst[m] * 2) + (u64)(k8 * 16)) = pk;
            return;
        }
        tid -= cnt;
    }
}

// ---------------------------------------------------------------------------
// qmlp: Q = elu(F@qW1+qb1)@qW2+qb2 -> bf16 LINEAR Q ; 128 rows, 512 thr
// ---------------------------------------------------------------------------
__device__ __forceinline__ void gemm2x4G(const char* __restrict__ Wt, int kstride, int kbase,
                                         const u16* B, f32x4 acc[2][4], int m0, int n0, int l){
    bf16x8 aw[4][2];
    #pragma unroll
    for (int kk = 0; kk < 4; kk++)
        #pragma unroll
        for (int i = 0; i < 2; i++)
            aw[kk][i] = ldfragG(Wt, m0 + i * 16, kstride, kbase + kk * 32, l);
    __builtin_amdgcn_s_setprio(1);
    #pragma unroll
    for (int kk = 0; kk < 4; kk++){
        #pragma unroll
        for (int nt = 0; nt < 4; nt++){
            bf16x8 b = ldfrag(B, n0 + nt * 16, kk * 32, l);
            #pragma unroll
            for (int mt = 0; mt < 2; mt++)
                acc[mt][nt] = __builtin_amdgcn_mfma_f32_16x16x32_bf16(aw[kk][mt], b, acc[mt][nt], 0, 0, 0);
        }
    }
    __builtin_amdgcn_s_setprio(0);
}

__global__ __launch_bounds__(512, 2) void qmlp_kernel(
    const float* __restrict__ F, const float* __restrict__ qb1, const float* __restrict__ qb2,
    const char* __restrict__ ws, u16* __restrict__ Qg, int n)
{
    __shared__ __align__(16) u16 sIn[16384];  // [128][128]
    __shared__ __align__(16) u16 sH[16384];
    const int t = threadIdx.x;
    const int row0 = blockIdx.x * 128;
    const int l = t & 63, w = t >> 6;
    const int m0 = (w & 3) * 32, n0 = (w >> 2) * 64;
    const int hi = l >> 4;

    for (int i = t; i < 4096; i += 512){
        int r = i >> 5, c = (i & 31) * 4;
        int gr = row0 + r;
        float4 v = make_float4(0.f, 0.f, 0.f, 0.f);
        if (gr < n) v = *(const float4*)&F[(size_t)gr * ND + c];
        *(u32x2*)((char*)sIn + (r << 8) + (((c << 1)) ^ ((r & 7) << 4))) = cvt4(v.x, v.y, v.z, v.w);
    }
    SBAR();

    {
        f32x4 acc[2][4];
        bias_init2(acc, qb1, m0, hi);
        gemm2x4G(ws + OFF_QW1T, 256, 0, sIn, acc, m0, n0, l);
        #pragma unroll
        for (int mt = 0; mt < 2; mt++){
            int ch0 = m0 + mt * 16 + (hi << 2);
            #pragma unroll
            for (int nt = 0; nt < 4; nt++){
                int row = n0 + nt * 16 + (l & 15);
                *(u32x2*)((char*)sH + (row << 8) + (((ch0 << 1)) ^ ((row & 7) << 4))) =
                    cvt4(elu_f(acc[mt][nt][0]), elu_f(acc[mt][nt][1]),
                         elu_f(acc[mt][nt][2]), elu_f(acc[mt][nt][3]));
            }
        }
    }
    SBAR();

    for (int ct = 0; ct < 8; ct++){
        f32x4 a2[2][4];
        bias_init2(a2, qb2 + ct * 128, m0, hi);
        gemm2x4G(ws + OFF_QW2T + (u64)ct * 32768ULL, 256, 0, sH, a2, m0, n0, l);
        #pragma unroll
        for (int mt = 0; mt < 2; mt++){
            int ch0 = m0 + mt * 16 + (hi << 2);
            #pragma unroll
            for (int nt = 0; nt < 4; nt++){
                int row = n0 + nt * 16 + (l & 15);
                int gr = row0 + row;
                if (gr < n)
                    *(u64*)((char*)Qg + (size_t)gr * 2048 + (size_t)((ct * 128 + ch0) * 2)) =
                        __builtin_bit_cast(u64, cvt4(a2[mt][nt][0], a2[mt][nt][1],
                                                     a2[mt][nt][2], a2[mt][nt][3]));
            }
        }
    }
}

// ---------------------------------------------------------------------------
// attn: PERSISTENT blocks, weights in VGPRs; 4 pts/group, 256 thr, 4 waves
// R16: Q prefetched to registers at group-loop head (hides ~300-900cy load
// latency under ~20K cycles of geometry+layer work before the QK phase).
// ---------------------------------------------------------------------------
__global__ __launch_bounds__(256, 2) void attn_kernel(
    const float* __restrict__ F, const float* __restrict__ X,
    const float* __restrict__ NUV, const int* __restrict__ TOPK,
    const float* __restrict__ gb1, const float* __restrict__ gb2,
    const float* __restrict__ kb1, const float* __restrict__ kb2,
    const float* __restrict__ vb1, const float* __restrict__ vb2,
    const char* __restrict__ ws, const u16* __restrict__ Qg, u16* __restrict__ ATT,
    int ngroups)
{
    __shared__ __align__(16) u16 bufA[16384];  // [128][128]
    __shared__ __align__(16) u16 bufB[16384];  // [128][128] (RL [128][32] at group start)
    __shared__ __align__(16) u16 sP16[2048];   // 4 pts x [16 h][32 k] (64B rows, keyed)
    __shared__ float sdis[128];
    __shared__ int   sidx[128];

    const int t = threadIdx.x;
    const int l = t & 63, w = t >> 6;
    const int m0 = w * 32;          // this wave's 32-channel slice
    const int hi = l >> 4;

    // ---- load ALL weights into registers once (persist across group loop) ----
    bf16x8 ag[2];                   // gW1t [128][32]: 64B rows
    #pragma unroll
    for (int i = 0; i < 2; i++)
        ag[i] = *(const bf16x8*)(ws + OFF_GW1T
                 + (u64)((m0 + i * 16 + (l & 15)) * 64 + (hi << 4)));
    bf16x8 wg2[4][2], wk1[4][2], wk2[4][2], wv1[4][2], wv2[4][2];
    #pragma unroll
    for (int kk = 0; kk < 4; kk++)
        #pragma unroll
        for (int i = 0; i < 2; i++){
            u64 fo = (u64)((m0 + i * 16 + (l & 15)) * 256 + kk * 64 + (hi << 4));
            wg2[kk][i] = *(const bf16x8*)(ws + OFF_GW2T + fo);
            wk1[kk][i] = *(const bf16x8*)(ws + OFF_KW1T + fo);
            wk2[kk][i] = *(const bf16x8*)(ws + OFF_KW2T + fo);
            wv1[kk][i] = *(const bf16x8*)(ws + OFF_VW1T + fo);
            wv2[kk][i] = *(const bf16x8*)(ws + OFF_VW2T + fo);
        }

    for (int g = blockIdx.x; g < ngroups; g += gridDim.x){
        const int pid0 = g * 4;

        // prefetch this group's Q fragments (consumed ~6 phases later in QK);
        // registers only, read-only global data -> race-free.
        bf16x8 qreg[4];
        {
            const char* qb = (const char*)Qg + (size_t)(pid0 + w) * 2048
                           + (size_t)(l & 7) * 256 + (size_t)(hi << 4);
            #pragma unroll
            for (int kk = 0; kk < 4; kk++)
                qreg[kk] = *(const bf16x8*)(qb + kk * 64);
        }

        SBAR();   // previous group's PV reads of bufB done before geometry writes

        // geometry: RL -> bufB [128][32], dis, idx
        if (t < 128){
            int p = t >> 5, k = t & 31;
            int pid = pid0 + p;
            int idx = TOPK[(size_t)pid * NNB + k];
            sidx[t] = idx;
            float x0 = X[(size_t)pid * 3 + 0], x1 = X[(size_t)pid * 3 + 1], x2 = X[(size_t)pid * 3 + 2];
            float ox = X[(size_t)idx * 3 + 0] - x0;
            float oy = X[(size_t)idx * 3 + 1] - x1;
            float oz = X[(size_t)idx * 3 + 2] - x2;
            sdis[t] = __expf(-0.5f * (ox * ox + oy * oy + oz * oz));
            float nv[9];
            #pragma unroll
            for (int i = 0; i < 9; i++) nv[i] = NUV[(size_t)pid * 9 + i];
            float f[12];
            #pragma unroll
            for (int i = 0; i < 3; i++)
                f[i] = nv[i * 3 + 0] * ox + nv[i * 3 + 1] * oy + nv[i * 3 + 2] * oz;
            #pragma unroll
            for (int r = 0; r < 3; r++){
                float a0 = NUV[(size_t)idx * 9 + r * 3 + 0];
                float a1 = NUV[(size_t)idx * 9 + r * 3 + 1];
                float a2 = NUV[(size_t)idx * 9 + r * 3 + 2];
                #pragma unroll
                for (int i = 0; i < 3; i++)
                    f[3 + r * 3 + i] = nv[i * 3 + 0] * a0 + nv[i * 3 + 1] * a1 + nv[i * 3 + 2] * a2;
            }
            char* rb = (char*)bufB + (t << 6);
            u32 key = (u32)(t & 3) << 4;
            *(u32x2*)(rb + (0u ^ key))  = cvt4(f[0], f[1], f[2], f[3]);
            *(u32x2*)(rb + (8u ^ key))  = cvt4(f[4], f[5], f[6], f[7]);
            *(u32x2*)(rb + (16u ^ key)) = cvt4(f[8], f[9], f[10], f[11]);
            *(u32x2*)(rb + (24u ^ key)) = (u32x2){0u, 0u};
            *(u32x2*)(rb + (32u ^ key)) = (u32x2){0u, 0u};
            *(u32x2*)(rb + (40u ^ key)) = (u32x2){0u, 0u};
            *(u32x2*)(rb + (48u ^ key)) = (u32x2){0u, 0u};
            *(u32x2*)(rb + (56u ^ key)) = (u32x2){0u, 0u};
        }
        SBAR();

        // geo L1 (K=32): bufB(RL) -> bufA, elu
        #pragma unroll
        for (int half = 0; half < 2; half++){
            f32x4 acc[2][4];
            bias_init2(acc, gb1, m0, hi);
            __builtin_amdgcn_s_setprio(1);
            #pragma unroll
            for (int nt = 0; nt < 4; nt++){
                bf16x8 bg = ldfragRL(bufB, half * 64 + nt * 16, l);
                acc[0][nt] = __builtin_amdgcn_mfma_f32_16x16x32_bf16(ag[0], bg, acc[0][nt], 0, 0, 0);
                acc[1][nt] = __builtin_amdgcn_mfma_f32_16x16x32_bf16(ag[1], bg, acc[1][nt], 0, 0, 0);
            }
            __builtin_amdgcn_s_setprio(0);
            #pragma unroll
            for (int mt = 0; mt < 2; mt++){
                int ch0 = m0 + mt * 16 + (hi << 2);
                #pragma unroll
                for (int nt = 0; nt < 4; nt++){
                    int row = half * 64 + nt * 16 + (l & 15);
                    *(u32x2*)((char*)bufA + (row << 8) + (((ch0 << 1)) ^ ((row & 7) << 4))) =
                        cvt4(elu_f(acc[mt][nt][0]), elu_f(acc[mt][nt][1]),
                             elu_f(acc[mt][nt][2]), elu_f(acc[mt][nt][3]));
                }
            }
        }
        SBAR();

        layerP<2, false>(bufA, bufB, wg2, gb2, F, sidx, sdis, m0, l, hi); // geo L2 -> G(bufB)
        layerP<1, false>(bufB, bufA, wk1, kb1, F, sidx, sdis, m0, l, hi); // K1 -> bufA
        layerP<0, true >(bufA, bufA, wk2, kb2, F, sidx, sdis, m0, l, hi); // K2 in-place -> K

        // QK + softmax: wave w = point w (Q from prefetched registers)
        {
            f32x4 s0, s1;
            s0 = 0.f; s1 = 0.f;
            #pragma unroll
            for (int kk = 0; kk < 4; kk++){
                bf16x8 a0 = ldfrag(bufA, w * 32,      kk * 32, l);
                bf16x8 a1 = ldfrag(bufA, w * 32 + 16, kk * 32, l);
                s0 = __builtin_amdgcn_mfma_f32_16x16x32_bf16(a0, qreg[kk], s0, 0, 0, 0);
                s1 = __builtin_amdgcn_mfma_f32_16x16x32_bf16(a1, qreg[kk], s1, 0, 0, 0);
            }
            const float RS = 0.08838834764831845f;
            float sv[8];
            #pragma unroll
            for (int mt = 0; mt < 2; mt++)
                #pragma unroll
                for (int j = 0; j < 4; j++){
                    int kidx = mt * 16 + (hi << 2) + j;
                    float x = (mt ? s1[j] : s0[j]) * RS;
                    if (sidx[w * 32 + kidx] == 0) x = -INFINITY;
                    sv[mt * 4 + j] = x;
                }
            float mx = sv[0];
            #pragma unroll
            for (int i = 1; i < 8; i++) mx = fmaxf(mx, sv[i]);
            mx = fmaxf(mx, __shfl_xor(mx, 16));
            mx = fmaxf(mx, __shfl_xor(mx, 32));
            float e[8], sum = 0.f;
            #pragma unroll
            for (int i = 0; i < 8; i++){ e[i] = __expf(sv[i] - mx); sum += e[i]; }
            sum += __shfl_xor(sum, 16);
            sum += __shfl_xor(sum, 32);
            float inv = 1.f / sum;
            int h = l & 15;
            u32 key = (u32)(h & 3) << 4;
            char* pb = (char*)sP16 + w * 1024 + h * 64;
            *(u32x2*)(pb + (((u32)(hi * 8)) ^ key)) =
                cvt4(e[0] * inv, e[1] * inv, e[2] * inv, e[3] * inv);
            *(u32x2*)(pb + (((u32)(32 + hi * 8)) ^ key)) =
                cvt4(e[4] * inv, e[5] * inv, e[6] * inv, e[7] * inv);
        }
        SBAR();

        layerP<1, false>(bufB, bufA, wv1, vb1, F, sidx, sdis, m0, l, hi); // V1 -> Hv(bufA)

        // V2: A = Hv rows(bufA), B = wv2 (registers) -> V^T in bufB [128 ch][128 kv]
        #pragma unroll
        for (int half = 0; half < 2; half++){
            f32x4 a2[4][2];
            #pragma unroll
            for (int ntc = 0; ntc < 2; ntc++){
                float bv = vb2[m0 + ntc * 16 + (l & 15)];
                #pragma unroll
                for (int mtr = 0; mtr < 4; mtr++)
                    a2[mtr][ntc] = (f32x4){bv, bv, bv, bv};
            }
            __builtin_amdgcn_s_setprio(1);
            #pragma unroll
            for (int kk = 0; kk < 4; kk++){
                #pragma unroll
                for (int mtr = 0; mtr < 4; mtr++){
                    bf16x8 a = ldfrag(bufA, half * 64 + mtr * 16, kk * 32, l);
                    #pragma unroll
                    for (int ntc = 0; ntc < 2; ntc++)
                        a2[mtr][ntc] = __builtin_amdgcn_mfma_f32_16x16x32_bf16(a, wv2[kk][ntc], a2[mtr][ntc], 0, 0, 0);
                }
            }
            __builtin_amdgcn_s_setprio(0);
            #pragma unroll
            for (int mtr = 0; mtr < 4; mtr++){
                int kv0 = half * 64 + mtr * 16 + (hi << 2);
                #pragma unroll
                for (int ntc = 0; ntc < 2; ntc++){
                    int ch = m0 + ntc * 16 + (l & 15);
                    *(u32x2*)((char*)bufB + (ch << 8) + (((kv0 << 1)) ^ ((ch & 7) << 4))) =
                        cvt4(a2[mtr][ntc][0], a2[mtr][ntc][1], a2[mtr][ntc][2], a2[mtr][ntc][3]);
                }
            }
        }
        SBAR();

        // PV: O^T = V^T(A) @ P^T(B) ; wave w = point w, full 128 ch
        {
            int pid = pid0 + w;
            int h = l & 15;
            bf16x8 pb = *(const bf16x8*)((const char*)sP16 + w * 1024 + h * 64
                                         + (((u32)(hi * 16)) ^ ((u32)(h & 3) << 4)));
            u32 key = ((u32)pid & 7) << 4;
            char* dst = (char*)ATT + (size_t)pid * 2048;
            #pragma unroll
            for (int nt = 0; nt < 8; nt++){
                f32x4 o;
                o = 0.f;
                bf16x8 av = ldfrag(bufB, nt * 16, w * 32, l);
                o = __builtin_amdgcn_mfma_f32_16x16x32_bf16(av, pb, o, 0, 0, 0);
                if (h < 8){
                    u32 dbyte = (u32)(nt * 32 + hi * 8);
                    *(u32x2*)(dst + h * 256 + (dbyte ^ key)) = cvt4(o[0], o[1], o[2], o[3]);
                }
            }
        }
    }
}

// ---------------------------------------------------------------------------
// decode: out = LN( elu(ATT@dW1+db1)@dW2+db2 + F ) * g + b ; 128 rows, 512 thr
// ---------------------------------------------------------------------------
__global__ __launch_bounds__(512, 2) void decode_kernel(
    const u16* __restrict__ ATT,
    const float* __restrict__ db1, const float* __restrict__ db2,
    const float* __restrict__ F,
    const float* __restrict__ lng, const float* __restrict__ lnb,
    const char* __restrict__ ws, float* __restrict__ OUT, int n)
{
    __shared__ __align__(16) char SM[67584];
    u16* sA = (u16*)SM;
    u16* sH = (u16*)(SM + 32768);
    float* sO = (float*)SM;

    const int t = threadIdx.x;
    const int row0 = blockIdx.x * 128;
    const int l = t & 63, w = t >> 6;
    const int m0 = (w & 3) * 32, n0 = (w >> 2) * 64;
    const int hi = l >> 4;

    f32x4 acc[2][4];
    bias_init2(acc, db1, m0, hi);
    for (int kc = 0; kc < 8; kc++){
        {
            const int seg = (t & 15) * 16, rr = t >> 4;
            const char* g = (const char*)ATT + (size_t)row0 * 2048 + kc * 256;
            #pragma unroll
            for (int i = 0; i < 4; i++){
                int row = i * 32 + rr;
                GLDS16(g + (size_t)row * 2048 + seg, (char*)sA + row * 256 + seg);
            }
        }
        __syncthreads();
        gemm2x4G(ws + OFF_DW1T, 2048, kc * 128, sA, acc, m0, n0, l);
        SBAR();
    }
    #pragma unroll
    for (int mt = 0; mt < 2; mt++){
        int ch0 = m0 + mt * 16 + (hi << 2);
        #pragma unroll
        for (int nt = 0; nt < 4; nt++){
            int row = n0 + nt * 16 + (l & 15);
            *(u32x2*)((char*)sH + (row << 8) + (((ch0 << 1)) ^ ((row & 7) << 4))) =
                cvt4(elu_f(acc[mt][nt][0]), elu_f(acc[mt][nt][1]),
                     elu_f(acc[mt][nt][2]), elu_f(acc[mt][nt][3]));
        }
    }
    SBAR();

    f32x4 a2[2][4];
    bias_init2(a2, db2, m0, hi);
    gemm2x4G(ws + OFF_DW2T, 256, 0, sH, a2, m0, n0, l);
    SBAR();

    #pragma unroll
    for (int mt = 0; mt < 2; mt++){
        int ch0 = m0 + mt * 16 + (hi << 2);
        #pragma unroll
        for (int nt = 0; nt < 4; nt++){
            int row = n0 + nt * 16 + (l & 15);
            int gr = row0 + row;
            float4 fres = make_float4(0.f, 0.f, 0.f, 0.f);
            if (gr < n) fres = *(const float4*)&F[(size_t)gr * ND + ch0];
            float4 ov = make_float4(a2[mt][nt][0] + fres.x, a2[mt][nt][1] + fres.y,
                                    a2[mt][nt][2] + fres.z, a2[mt][nt][3] + fres.w);
            *(float4*)&sO[row * 132 + ch0] = ov;
        }
    }
    SBAR();

    {
        int r = t >> 2, q = t & 3;
        const float* rowp = sO + r * 132 + q * 32;
        float s = 0.f;
        #pragma unroll
        for (int i = 0; i < 8; i++){
            float4 v = ((const float4*)rowp)[i];
            s += v.x + v.y + v.z + v.w;
        }
        s += __shfl_xor(s, 1);
        s += __shfl_xor(s, 2);
        float mu = s * (1.0f / 128.0f);
        float q2 = 0.f;
        #pragma unroll
        for (int i = 0; i < 8; i++){
            float4 v = ((const float4*)rowp)[i];
            q2 += (v.x - mu) * (v.x - mu) + (v.y - mu) * (v.y - mu)
                + (v.z - mu) * (v.z - mu) + (v.w - mu) * (v.w - mu);
        }
        q2 += __shfl_xor(q2, 1);
        q2 += __shfl_xor(q2, 2);
        float rstd = rsqrtf(q2 * (1.0f / 128.0f) + 1e-5f);
        int gr = row0 + r;
        if (gr < n){
            #pragma unroll
            for (int i = 0; i < 8; i++){
                float4 v = ((const float4*)rowp)[i];
                int c = q * 32 + i * 4;
                float4 g4 = *(const float4*)&lng[c];
                float4 b4 = *(const float4*)&lnb[c];
                float4 ov = make_float4((v.x - mu) * rstd * g4.x + b4.x,
                                        (v.y - mu) * rstd * g4.y + b4.y,
                                        (v.z - mu) * rstd * g4.z + b4.z,
                                        (v.w - mu) * rstd * g4.w + b4.w);
                *(float4*)&OUT[(size_t)gr * ND + c] = ov;
            }
        }
    }
}

// ---------------------------------------------------------------------------
extern "C" void kernel_launch(void* const* d_in, const int* in_sizes, int n_in,
                              void* d_out, int out_size, void* d_ws, size_t ws_size,
                              hipStream_t stream)
{
    const float* F    = (const float*)d_in[0];
    const float* X    = (const float*)d_in[1];
    const float* NUV  = (const float*)d_in[2];
    const int*   TOPK = (const int*)d_in[3];
    const float* qW1  = (const float*)d_in[4];
    const float* qb1  = (const float*)d_in[5];
    const float* qW2  = (const float*)d_in[6];
    const float* qb2  = (const float*)d_in[7];
    const float* gW1  = (const float*)d_in[8];
    const float* gb1  = (const float*)d_in[9];
    const float* gW2  = (const float*)d_in[10];
    const float* gb2  = (const float*)d_in[11];
    const float* kW1  = (const float*)d_in[12];
    const float* kb1  = (const float*)d_in[13];
    const float* kW2  = (const float*)d_in[14];
    const float* kb2  = (const float*)d_in[15];
    const float* vW1  = (const float*)d_in[16];
    const float* vb1  = (const float*)d_in[17];
    const float* vW2  = (const float*)d_in[18];
    const float* vb2  = (const float*)d_in[19];
    const float* dW1  = (const float*)d_in[20];
    const float* db1  = (const float*)d_in[21];
    const float* dW2  = (const float*)d_in[22];
    const float* db2  = (const float*)d_in[23];
    const float* lng  = (const float*)d_in[24];
    const float* lnb  = (const float*)d_in[25];

    const int n = in_sizes[0] / ND;
    char* wsb = (char*)d_ws;

    PrepDesc pd;
    const float* srcs[10] = {qW1, qW2, gW1, gW2, kW1, kW2, vW1, vW2, dW1, dW2};
    u64 offs[10] = {OFF_QW1T, OFF_QW2T, OFF_GW1T, OFF_GW2T, OFF_KW1T,
                    OFF_KW2T, OFF_VW1T, OFF_VW2T, OFF_DW1T, OFF_DW2T};
    int Ns[10]   = {128, 1024, 128, 128, 128, 128, 128, 128, 128, 128};
    int Ksrc[10] = {128, 128, 12, 128, 128, 128, 128, 128, 1024, 128};
    int Kdst[10] = {128, 128, 32, 128, 128, 128, 128, 128, 1024, 128};
    for (int i = 0; i < 10; i++){
        pd.src[i] = srcs[i]; pd.dstoff[i] = offs[i];
        pd.N[i] = Ns[i]; pd.Ksrc[i] = Ksrc[i]; pd.Kdst[i] = Kdst[i];
    }
    prep_weights<<<186, 256, 0, stream>>>(pd, wsb);

    u16* Qg  = (u16*)(wsb + OFF_Q);
    u16* ATT = (u16*)(wsb + OFF_ATT);
    const int nb = (n + 127) / 128;
    const int ngroups = n / 4;

    qmlp_kernel<<<nb, 512, 0, stream>>>(F, qb1, qb2, wsb, Qg, n);
    attn_kernel<<<512, 256, 0, stream>>>(F, X, NUV, TOPK, gb1, gb2,
                                         kb1, kb2, vb1, vb2, wsb, Qg, ATT, ngroups);
    decode_kernel<<<nb, 512, 0, stream>>>(ATT, db1, db2, F, lng, lnb, wsb, (float*)d_out, n);
}

// Round 17
// 392.865 us; speedup vs baseline: 1.0376x; 1.0376x over previous
//
#include <hip/hip_runtime.h>
#include <math.h>
#include <stdint.h>

#define ND 128
#define NNB 32
#define NH 8

typedef __attribute__((ext_vector_type(8))) short bf16x8;
typedef __attribute__((ext_vector_type(4))) float f32x4;
typedef __attribute__((ext_vector_type(8))) unsigned short u16x8;
typedef __attribute__((ext_vector_type(2))) unsigned int u32x2;
typedef unsigned short u16;
typedef unsigned int u32;
typedef unsigned long long u64;

// ---- ws layout (bytes); all weights transposed Wt[N][K] bf16, LINEAR ----
#define OFF_QW1T 0ULL
#define OFF_QW2T 32768ULL
#define OFF_GW1T 294912ULL     // [128][32] (K padded 12->32 with zeros)
#define OFF_GW2T 303104ULL
#define OFF_KW1T 335872ULL
#define OFF_KW2T 368640ULL
#define OFF_VW1T 401408ULL
#define OFF_VW2T 434176ULL
#define OFF_DW1T 466944ULL     // [128][1024]
#define OFF_DW2T 729088ULL
#define OFF_Q    761856ULL     // [20096][1024] bf16, linear
#define OFF_ATT  (OFF_Q + 20096ULL * 2048ULL)  // chunk-swizzled by (pid&7)

// soft barrier: drain LDS ops only (NOT vmcnt) then barrier.
#define SBAR() asm volatile("s_waitcnt lgkmcnt(0)\n\ts_barrier" ::: "memory")

__device__ __forceinline__ u16 rneb(float f){
    u32 u = __builtin_bit_cast(u32, f);
    u32 r = u + 0x7fffu + ((u >> 16) & 1u);
    return (u16)(r >> 16);
}
__device__ __forceinline__ float elu_f(float v){ return v > 0.f ? v : (__expf(v) - 1.f); }

__device__ __forceinline__ u32 cvtpk(float a, float b){
    u32 r;
    asm("v_cvt_pk_bf16_f32 %0, %1, %2" : "=v"(r) : "v"(a), "v"(b));
    return r;
}
__device__ __forceinline__ u32x2 cvt4(float a, float b, float c, float d){
    u32x2 r; r.x = cvtpk(a, b); r.y = cvtpk(c, d); return r;
}

// async global->LDS, 16B per lane (linear dest)
#define GLDS16(g, l) __builtin_amdgcn_global_load_lds( \
    (const __attribute__((address_space(1))) u32*)(g), \
    (__attribute__((address_space(3))) u32*)(u32)(u64)(l), 16, 0, 0)

// fragment read from LDS: row-major [*][128] bf16 (256B rows), byte ^= (r&7)<<4
__device__ __forceinline__ bf16x8 ldfrag(const u16* base, int row, int kb, int l){
    int r = row + (l & 15);
    int byte = (r << 8) + (((kb << 1) + ((l >> 4) << 4)) ^ ((r & 7) << 4));
    return *(const bf16x8*)((const char*)base + byte);
}
// 64B-row variant (RL tile [128][32]), byte ^= (r&3)<<4
__device__ __forceinline__ bf16x8 ldfragRL(const u16* base, int row, int l){
    int r = row + (l & 15);
    int byte = (r << 6) + ((((l >> 4) << 4)) ^ ((r & 3) << 4));
    return *(const bf16x8*)((const char*)base + byte);
}
// fragment directly from global Wt[N][K] (linear, row stride kstride bytes)
__device__ __forceinline__ bf16x8 ldfragG(const char* __restrict__ Wt, int n, int kstride, int kb, int l){
    return *(const bf16x8*)(Wt + (size_t)(n + (l & 15)) * (size_t)kstride
                               + (size_t)((kb << 1) + ((l >> 4) << 4)));
}

// gemm over one row-half (64 rows) with REGISTER-RESIDENT weights.
// wave tile: 32 out-ch (m0) x 64 rows. 16 ds_reads, 32 MFMA.
__device__ __forceinline__ void gemm_half(const bf16x8 aw[4][2], const u16* B,
                                          int nbase, f32x4 acc[2][4], int l){
    __builtin_amdgcn_s_setprio(1);
    #pragma unroll
    for (int kk = 0; kk < 4; kk++){
        #pragma unroll
        for (int nt = 0; nt < 4; nt++){
            bf16x8 b = ldfrag(B, nbase + nt * 16, kk * 32, l);
            acc[0][nt] = __builtin_amdgcn_mfma_f32_16x16x32_bf16(aw[kk][0], b, acc[0][nt], 0, 0, 0);
            acc[1][nt] = __builtin_amdgcn_mfma_f32_16x16x32_bf16(aw[kk][1], b, acc[1][nt], 0, 0, 0);
        }
    }
    __builtin_amdgcn_s_setprio(0);
}

__device__ __forceinline__ void bias_init2(f32x4 acc[2][4], const float* __restrict__ bias,
                                           int m0, int hi){
    #pragma unroll
    for (int mt = 0; mt < 2; mt++){
        float4 bq = *(const float4*)&bias[m0 + mt * 16 + (hi << 2)];
        #pragma unroll
        for (int nt = 0; nt < 4; nt++)
            acc[mt][nt] = (f32x4){bq.x, bq.y, bq.z, bq.w};
    }
}

// full layer, register-weights: ACT 0 linear, 1 elu, 2 linear*dis*F_nn
template<int ACT, bool INPLACE>
__device__ __forceinline__ void layerP(
    const u16* inB, u16* outB, const bf16x8 aw[4][2],
    const float* __restrict__ bias, const float* __restrict__ F,
    const int* sidx, const float* sdis, int m0, int l, int hi)
{
    #pragma unroll
    for (int half = 0; half < 2; half++){
        const int nbase = half * 64;
        float4 fv[2][4]; float ds[4];
        if (ACT == 2){
            #pragma unroll
            for (int nt = 0; nt < 4; nt++){
                int row = nbase + nt * 16 + (l & 15);
                int ix = sidx[row];
                ds[nt] = sdis[row];
                fv[0][nt] = *(const float4*)&F[(size_t)ix * ND + m0 + (hi << 2)];
                fv[1][nt] = *(const float4*)&F[(size_t)ix * ND + m0 + 16 + (hi << 2)];
            }
        }
        f32x4 acc[2][4];
        bias_init2(acc, bias, m0, hi);
        gemm_half(aw, inB, nbase, acc, l);
        if (INPLACE) SBAR();   // all waves' reads of this half done before writes
        #pragma unroll
        for (int mt = 0; mt < 2; mt++){
            int ch0 = m0 + mt * 16 + (hi << 2);
            #pragma unroll
            for (int nt = 0; nt < 4; nt++){
                int row = nbase + nt * 16 + (l & 15);
                float v0 = acc[mt][nt][0], v1 = acc[mt][nt][1];
                float v2 = acc[mt][nt][2], v3 = acc[mt][nt][3];
                if (ACT == 1){ v0 = elu_f(v0); v1 = elu_f(v1); v2 = elu_f(v2); v3 = elu_f(v3); }
                if (ACT == 2){
                    float s = ds[nt];
                    v0 *= s * fv[mt][nt].x; v1 *= s * fv[mt][nt].y;
                    v2 *= s * fv[mt][nt].z; v3 *= s * fv[mt][nt].w;
                }
                *(u32x2*)((char*)outB + (row << 8) + (((ch0 << 1)) ^ ((row & 7) << 4))) =
                    cvt4(v0, v1, v2, v3);
            }
        }
    }
    SBAR();
}

// ---------------------------------------------------------------------------
// prep: W (Ksrc x N f32) -> Wt (N x Kdst bf16, zero-padded), linear
// ---------------------------------------------------------------------------
struct PrepDesc {
    const float* src[10];
    u64 dstoff[10];
    int N[10], Ksrc[10], Kdst[10];
};

__global__ __launch_bounds__(256) void prep_weights(PrepDesc d, char* ws){
    int tid = blockIdx.x * 256 + threadIdx.x;
    #pragma unroll 1
    for (int m = 0; m < 10; m++){
        int cnt = (d.Kdst[m] * d.N[m]) >> 3;
        if (tid < cnt){
            int N = d.N[m];
            int nn = tid % N, k8 = tid / N;
            const float* s = d.src[m];
            u16x8 pk;
            #pragma unroll
            for (int i = 0; i < 8; i++){
                int k = k8 * 8 + i;
                pk[i] = (k < d.Ksrc[m]) ? rneb(s[(size_t)k * N + nn]) : (u16)0;
            }
            *(u16x8*)(ws + d.dstoff[m] + (u64)nn * (u64)(d.Kdst[m] * 2) + (u64)(k8 * 16)) = pk;
            return;
        }
        tid -= cnt;
    }
}

// ---------------------------------------------------------------------------
// qmlp: Q = elu(F@qW1+qb1)@qW2+qb2 -> bf16 LINEAR Q ; 128 rows, 512 thr
// ---------------------------------------------------------------------------
__device__ __forceinline__ void gemm2x4G(const char* __restrict__ Wt, int kstride, int kbase,
                                         const u16* B, f32x4 acc[2][4], int m0, int n0, int l){
    bf16x8 aw[4][2];
    #pragma unroll
    for (int kk = 0; kk < 4; kk++)
        #pragma unroll
        for (int i = 0; i < 2; i++)
            aw[kk][i] = ldfragG(Wt, m0 + i * 16, kstride, kbase + kk * 32, l);
    __builtin_amdgcn_s_setprio(1);
    #pragma unroll
    for (int kk = 0; kk < 4; kk++){
        #pragma unroll
        for (int nt = 0; nt < 4; nt++){
            bf16x8 b = ldfrag(B, n0 + nt * 16, kk * 32, l);
            #pragma unroll
            for (int mt = 0; mt < 2; mt++)
                acc[mt][nt] = __builtin_amdgcn_mfma_f32_16x16x32_bf16(aw[kk][mt], b, acc[mt][nt], 0, 0, 0);
        }
    }
    __builtin_amdgcn_s_setprio(0);
}

__global__ __launch_bounds__(512, 2) void qmlp_kernel(
    const float* __restrict__ F, const float* __restrict__ qb1, const float* __restrict__ qb2,
    const char* __restrict__ ws, u16* __restrict__ Qg, int n)
{
    __shared__ __align__(16) u16 sIn[16384];  // [128][128]
    __shared__ __align__(16) u16 sH[16384];
    const int t = threadIdx.x;
    const int row0 = blockIdx.x * 128;
    const int l = t & 63, w = t >> 6;
    const int m0 = (w & 3) * 32, n0 = (w >> 2) * 64;
    const int hi = l >> 4;

    for (int i = t; i < 4096; i += 512){
        int r = i >> 5, c = (i & 31) * 4;
        int gr = row0 + r;
        float4 v = make_float4(0.f, 0.f, 0.f, 0.f);
        if (gr < n) v = *(const float4*)&F[(size_t)gr * ND + c];
        *(u32x2*)((char*)sIn + (r << 8) + (((c << 1)) ^ ((r & 7) << 4))) = cvt4(v.x, v.y, v.z, v.w);
    }
    SBAR();

    {
        f32x4 acc[2][4];
        bias_init2(acc, qb1, m0, hi);
        gemm2x4G(ws + OFF_QW1T, 256, 0, sIn, acc, m0, n0, l);
        #pragma unroll
        for (int mt = 0; mt < 2; mt++){
            int ch0 = m0 + mt * 16 + (hi << 2);
            #pragma unroll
            for (int nt = 0; nt < 4; nt++){
                int row = n0 + nt * 16 + (l & 15);
                *(u32x2*)((char*)sH + (row << 8) + (((ch0 << 1)) ^ ((row & 7) << 4))) =
                    cvt4(elu_f(acc[mt][nt][0]), elu_f(acc[mt][nt][1]),
                         elu_f(acc[mt][nt][2]), elu_f(acc[mt][nt][3]));
            }
        }
    }
    SBAR();

    for (int ct = 0; ct < 8; ct++){
        f32x4 a2[2][4];
        bias_init2(a2, qb2 + ct * 128, m0, hi);
        gemm2x4G(ws + OFF_QW2T + (u64)ct * 32768ULL, 256, 0, sH, a2, m0, n0, l);
        #pragma unroll
        for (int mt = 0; mt < 2; mt++){
            int ch0 = m0 + mt * 16 + (hi << 2);
            #pragma unroll
            for (int nt = 0; nt < 4; nt++){
                int row = n0 + nt * 16 + (l & 15);
                int gr = row0 + row;
                if (gr < n)
                    *(u64*)((char*)Qg + (size_t)gr * 2048 + (size_t)((ct * 128 + ch0) * 2)) =
                        __builtin_bit_cast(u64, cvt4(a2[mt][nt][0], a2[mt][nt][1],
                                                     a2[mt][nt][2], a2[mt][nt][3]));
            }
        }
    }
}

// ---------------------------------------------------------------------------
// attn: PERSISTENT blocks, weights in VGPRs; 4 pts/group, 256 thr, 4 waves
// ---------------------------------------------------------------------------
__global__ __launch_bounds__(256, 2)
__attribute__((amdgpu_waves_per_eu(2, 2)))
void attn_kernel(
    const float* __restrict__ F, const float* __restrict__ X,
    const float* __restrict__ NUV, const int* __restrict__ TOPK,
    const float* __restrict__ gb1, const float* __restrict__ gb2,
    const float* __restrict__ kb1, const float* __restrict__ kb2,
    const float* __restrict__ vb1, const float* __restrict__ vb2,
    const char* __restrict__ ws, const u16* __restrict__ Qg, u16* __restrict__ ATT,
    int ngroups)
{
    __shared__ __align__(16) u16 bufA[16384];  // [128][128]
    __shared__ __align__(16) u16 bufB[16384];  // [128][128] (RL [128][32] at group start)
    __shared__ __align__(16) u16 sP16[2048];   // 4 pts x [16 h][32 k] (64B rows, keyed)
    __shared__ float sdis[128];
    __shared__ int   sidx[128];

    const int t = threadIdx.x;
    const int l = t & 63, w = t >> 6;
    const int m0 = w * 32;          // this wave's 32-channel slice
    const int hi = l >> 4;

    // ---- load ALL weights into registers once (persist across group loop) ----
    bf16x8 ag[2];                   // gW1t [128][32]: 64B rows
    #pragma unroll
    for (int i = 0; i < 2; i++)
        ag[i] = *(const bf16x8*)(ws + OFF_GW1T
                 + (u64)((m0 + i * 16 + (l & 15)) * 64 + (hi << 4)));
    bf16x8 wg2[4][2], wk1[4][2], wk2[4][2], wv1[4][2], wv2[4][2];
    #pragma unroll
    for (int kk = 0; kk < 4; kk++)
        #pragma unroll
        for (int i = 0; i < 2; i++){
            u64 fo = (u64)((m0 + i * 16 + (l & 15)) * 256 + kk * 64 + (hi << 4));
            wg2[kk][i] = *(const bf16x8*)(ws + OFF_GW2T + fo);
            wk1[kk][i] = *(const bf16x8*)(ws + OFF_KW1T + fo);
            wk2[kk][i] = *(const bf16x8*)(ws + OFF_KW2T + fo);
            wv1[kk][i] = *(const bf16x8*)(ws + OFF_VW1T + fo);
            wv2[kk][i] = *(const bf16x8*)(ws + OFF_VW2T + fo);
        }

    for (int g = blockIdx.x; g < ngroups; g += gridDim.x){
        const int pid0 = g * 4;
        SBAR();   // previous group's PV reads of bufB done before geometry writes

        // geometry: RL -> bufB [128][32], dis, idx
        if (t < 128){
            int p = t >> 5, k = t & 31;
            int pid = pid0 + p;
            int idx = TOPK[(size_t)pid * NNB + k];
            sidx[t] = idx;
            float x0 = X[(size_t)pid * 3 + 0], x1 = X[(size_t)pid * 3 + 1], x2 = X[(size_t)pid * 3 + 2];
            float ox = X[(size_t)idx * 3 + 0] - x0;
            float oy = X[(size_t)idx * 3 + 1] - x1;
            float oz = X[(size_t)idx * 3 + 2] - x2;
            sdis[t] = __expf(-0.5f * (ox * ox + oy * oy + oz * oz));
            float nv[9];
            #pragma unroll
            for (int i = 0; i < 9; i++) nv[i] = NUV[(size_t)pid * 9 + i];
            float f[12];
            #pragma unroll
            for (int i = 0; i < 3; i++)
                f[i] = nv[i * 3 + 0] * ox + nv[i * 3 + 1] * oy + nv[i * 3 + 2] * oz;
            #pragma unroll
            for (int r = 0; r < 3; r++){
                float a0 = NUV[(size_t)idx * 9 + r * 3 + 0];
                float a1 = NUV[(size_t)idx * 9 + r * 3 + 1];
                float a2 = NUV[(size_t)idx * 9 + r * 3 + 2];
                #pragma unroll
                for (int i = 0; i < 3; i++)
                    f[3 + r * 3 + i] = nv[i * 3 + 0] * a0 + nv[i * 3 + 1] * a1 + nv[i * 3 + 2] * a2;
            }
            char* rb = (char*)bufB + (t << 6);
            u32 key = (u32)(t & 3) << 4;
            *(u32x2*)(rb + (0u ^ key))  = cvt4(f[0], f[1], f[2], f[3]);
            *(u32x2*)(rb + (8u ^ key))  = cvt4(f[4], f[5], f[6], f[7]);
            *(u32x2*)(rb + (16u ^ key)) = cvt4(f[8], f[9], f[10], f[11]);
            *(u32x2*)(rb + (24u ^ key)) = (u32x2){0u, 0u};
            *(u32x2*)(rb + (32u ^ key)) = (u32x2){0u, 0u};
            *(u32x2*)(rb + (40u ^ key)) = (u32x2){0u, 0u};
            *(u32x2*)(rb + (48u ^ key)) = (u32x2){0u, 0u};
            *(u32x2*)(rb + (56u ^ key)) = (u32x2){0u, 0u};
        }
        SBAR();

        // geo L1 (K=32): bufB(RL) -> bufA, elu
        #pragma unroll
        for (int half = 0; half < 2; half++){
            f32x4 acc[2][4];
            bias_init2(acc, gb1, m0, hi);
            __builtin_amdgcn_s_setprio(1);
            #pragma unroll
            for (int nt = 0; nt < 4; nt++){
                bf16x8 bg = ldfragRL(bufB, half * 64 + nt * 16, l);
                acc[0][nt] = __builtin_amdgcn_mfma_f32_16x16x32_bf16(ag[0], bg, acc[0][nt], 0, 0, 0);
                acc[1][nt] = __builtin_amdgcn_mfma_f32_16x16x32_bf16(ag[1], bg, acc[1][nt], 0, 0, 0);
            }
            __builtin_amdgcn_s_setprio(0);
            #pragma unroll
            for (int mt = 0; mt < 2; mt++){
                int ch0 = m0 + mt * 16 + (hi << 2);
                #pragma unroll
                for (int nt = 0; nt < 4; nt++){
                    int row = half * 64 + nt * 16 + (l & 15);
                    *(u32x2*)((char*)bufA + (row << 8) + (((ch0 << 1)) ^ ((row & 7) << 4))) =
                        cvt4(elu_f(acc[mt][nt][0]), elu_f(acc[mt][nt][1]),
                             elu_f(acc[mt][nt][2]), elu_f(acc[mt][nt][3]));
                }
            }
        }
        SBAR();

        layerP<2, false>(bufA, bufB, wg2, gb2, F, sidx, sdis, m0, l, hi); // geo L2 -> G(bufB)
        layerP<1, false>(bufB, bufA, wk1, kb1, F, sidx, sdis, m0, l, hi); // K1 -> bufA
        layerP<0, true >(bufA, bufA, wk2, kb2, F, sidx, sdis, m0, l, hi); // K2 in-place -> K

        // QK + softmax: wave w = point w
        {
            f32x4 s0, s1;
            s0 = 0.f; s1 = 0.f;
            const char* qb = (const char*)Qg + (size_t)(pid0 + w) * 2048
                           + (size_t)(l & 7) * 256 + (size_t)(hi << 4);
            #pragma unroll
            for (int kk = 0; kk < 4; kk++){
                bf16x8 bq = *(const bf16x8*)(qb + kk * 64);
                bf16x8 a0 = ldfrag(bufA, w * 32,      kk * 32, l);
                bf16x8 a1 = ldfrag(bufA, w * 32 + 16, kk * 32, l);
                s0 = __builtin_amdgcn_mfma_f32_16x16x32_bf16(a0, bq, s0, 0, 0, 0);
                s1 = __builtin_amdgcn_mfma_f32_16x16x32_bf16(a1, bq, s1, 0, 0, 0);
            }
            const float RS = 0.08838834764831845f;
            float sv[8];
            #pragma unroll
            for (int mt = 0; mt < 2; mt++)
                #pragma unroll
                for (int j = 0; j < 4; j++){
                    int kidx = mt * 16 + (hi << 2) + j;
                    float x = (mt ? s1[j] : s0[j]) * RS;
                    if (sidx[w * 32 + kidx] == 0) x = -INFINITY;
                    sv[mt * 4 + j] = x;
                }
            float mx = sv[0];
            #pragma unroll
            for (int i = 1; i < 8; i++) mx = fmaxf(mx, sv[i]);
            mx = fmaxf(mx, __shfl_xor(mx, 16));
            mx = fmaxf(mx, __shfl_xor(mx, 32));
            float e[8], sum = 0.f;
            #pragma unroll
            for (int i = 0; i < 8; i++){ e[i] = __expf(sv[i] - mx); sum += e[i]; }
            sum += __shfl_xor(sum, 16);
            sum += __shfl_xor(sum, 32);
            float inv = 1.f / sum;
            int h = l & 15;
            u32 key = (u32)(h & 3) << 4;
            char* pb = (char*)sP16 + w * 1024 + h * 64;
            *(u32x2*)(pb + (((u32)(hi * 8)) ^ key)) =
                cvt4(e[0] * inv, e[1] * inv, e[2] * inv, e[3] * inv);
            *(u32x2*)(pb + (((u32)(32 + hi * 8)) ^ key)) =
                cvt4(e[4] * inv, e[5] * inv, e[6] * inv, e[7] * inv);
        }
        SBAR();

        layerP<1, false>(bufB, bufA, wv1, vb1, F, sidx, sdis, m0, l, hi); // V1 -> Hv(bufA)

        // V2: A = Hv rows(bufA), B = wv2 (registers) -> V^T in bufB [128 ch][128 kv]
        #pragma unroll
        for (int half = 0; half < 2; half++){
            f32x4 a2[4][2];
            #pragma unroll
            for (int ntc = 0; ntc < 2; ntc++){
                float bv = vb2[m0 + ntc * 16 + (l & 15)];
                #pragma unroll
                for (int mtr = 0; mtr < 4; mtr++)
                    a2[mtr][ntc] = (f32x4){bv, bv, bv, bv};
            }
            __builtin_amdgcn_s_setprio(1);
            #pragma unroll
            for (int kk = 0; kk < 4; kk++){
                #pragma unroll
                for (int mtr = 0; mtr < 4; mtr++){
                    bf16x8 a = ldfrag(bufA, half * 64 + mtr * 16, kk * 32, l);
                    #pragma unroll
                    for (int ntc = 0; ntc < 2; ntc++)
                        a2[mtr][ntc] = __builtin_amdgcn_mfma_f32_16x16x32_bf16(a, wv2[kk][ntc], a2[mtr][ntc], 0, 0, 0);
                }
            }
            __builtin_amdgcn_s_setprio(0);
            #pragma unroll
            for (int mtr = 0; mtr < 4; mtr++){
                int kv0 = half * 64 + mtr * 16 + (hi << 2);
                #pragma unroll
                for (int ntc = 0; ntc < 2; ntc++){
                    int ch = m0 + ntc * 16 + (l & 15);
                    *(u32x2*)((char*)bufB + (ch << 8) + (((kv0 << 1)) ^ ((ch & 7) << 4))) =
                        cvt4(a2[mtr][ntc][0], a2[mtr][ntc][1], a2[mtr][ntc][2], a2[mtr][ntc][3]);
                }
            }
        }
        SBAR();

        // PV: O^T = V^T(A) @ P^T(B) ; wave w = point w, full 128 ch
        {
            int pid = pid0 + w;
            int h = l & 15;
            bf16x8 pb = *(const bf16x8*)((const char*)sP16 + w * 1024 + h * 64
                                         + (((u32)(hi * 16)) ^ ((u32)(h & 3) << 4)));
            u32 key = ((u32)pid & 7) << 4;
            char* dst = (char*)ATT + (size_t)pid * 2048;
            #pragma unroll
            for (int nt = 0; nt < 8; nt++){
                f32x4 o;
                o = 0.f;
                bf16x8 av = ldfrag(bufB, nt * 16, w * 32, l);
                o = __builtin_amdgcn_mfma_f32_16x16x32_bf16(av, pb, o, 0, 0, 0);
                if (h < 8){
                    u32 dbyte = (u32)(nt * 32 + hi * 8);
                    *(u32x2*)(dst + h * 256 + (dbyte ^ key)) = cvt4(o[0], o[1], o[2], o[3]);
                }
            }
        }
    }
}

// ---------------------------------------------------------------------------
// decode: out = LN( elu(ATT@dW1+db1)@dW2+db2 + F ) * g + b ; 128 rows, 512 thr
// ---------------------------------------------------------------------------
__global__ __launch_bounds__(512, 2) void decode_kernel(
    const u16* __restrict__ ATT,
    const float* __restrict__ db1, const float* __restrict__ db2,
    const float* __restrict__ F,
    const float* __restrict__ lng, const float* __restrict__ lnb,
    const char* __restrict__ ws, float* __restrict__ OUT, int n)
{
    __shared__ __align__(16) char SM[67584];
    u16* sA = (u16*)SM;
    u16* sH = (u16*)(SM + 32768);
    float* sO = (float*)SM;

    const int t = threadIdx.x;
    const int row0 = blockIdx.x * 128;
    const int l = t & 63, w = t >> 6;
    const int m0 = (w & 3) * 32, n0 = (w >> 2) * 64;
    const int hi = l >> 4;

    f32x4 acc[2][4];
    bias_init2(acc, db1, m0, hi);
    for (int kc = 0; kc < 8; kc++){
        {
            const int seg = (t & 15) * 16, rr = t >> 4;
            const char* g = (const char*)ATT + (size_t)row0 * 2048 + kc * 256;
            #pragma unroll
            for (int i = 0; i < 4; i++){
                int row = i * 32 + rr;
                GLDS16(g + (size_t)row * 2048 + seg, (char*)sA + row * 256 + seg);
            }
        }
        __syncthreads();
        gemm2x4G(ws + OFF_DW1T, 2048, kc * 128, sA, acc, m0, n0, l);
        SBAR();
    }
    #pragma unroll
    for (int mt = 0; mt < 2; mt++){
        int ch0 = m0 + mt * 16 + (hi << 2);
        #pragma unroll
        for (int nt = 0; nt < 4; nt++){
            int row = n0 + nt * 16 + (l & 15);
            *(u32x2*)((char*)sH + (row << 8) + (((ch0 << 1)) ^ ((row & 7) << 4))) =
                cvt4(elu_f(acc[mt][nt][0]), elu_f(acc[mt][nt][1]),
                     elu_f(acc[mt][nt][2]), elu_f(acc[mt][nt][3]));
        }
    }
    SBAR();

    f32x4 a2[2][4];
    bias_init2(a2, db2, m0, hi);
    gemm2x4G(ws + OFF_DW2T, 256, 0, sH, a2, m0, n0, l);
    SBAR();

    #pragma unroll
    for (int mt = 0; mt < 2; mt++){
        int ch0 = m0 + mt * 16 + (hi << 2);
        #pragma unroll
        for (int nt = 0; nt < 4; nt++){
            int row = n0 + nt * 16 + (l & 15);
            int gr = row0 + row;
            float4 fres = make_float4(0.f, 0.f, 0.f, 0.f);
            if (gr < n) fres = *(const float4*)&F[(size_t)gr * ND + ch0];
            float4 ov = make_float4(a2[mt][nt][0] + fres.x, a2[mt][nt][1] + fres.y,
                                    a2[mt][nt][2] + fres.z, a2[mt][nt][3] + fres.w);
            *(float4*)&sO[row * 132 + ch0] = ov;
        }
    }
    SBAR();

    {
        int r = t >> 2, q = t & 3;
        const float* rowp = sO + r * 132 + q * 32;
        float s = 0.f;
        #pragma unroll
        for (int i = 0; i < 8; i++){
            float4 v = ((const float4*)rowp)[i];
            s += v.x + v.y + v.z + v.w;
        }
        s += __shfl_xor(s, 1);
        s += __shfl_xor(s, 2);
        float mu = s * (1.0f / 128.0f);
        float q2 = 0.f;
        #pragma unroll
        for (int i = 0; i < 8; i++){
            float4 v = ((const float4*)rowp)[i];
            q2 += (v.x - mu) * (v.x - mu) + (v.y - mu) * (v.y - mu)
                + (v.z - mu) * (v.z - mu) + (v.w - mu) * (v.w - mu);
        }
        q2 += __shfl_xor(q2, 1);
        q2 += __shfl_xor(q2, 2);
        float rstd = rsqrtf(q2 * (1.0f / 128.0f) + 1e-5f);
        int gr = row0 + r;
        if (gr < n){
            #pragma unroll
            for (int i = 0; i < 8; i++){
                float4 v = ((const float4*)rowp)[i];
                int c = q * 32 + i * 4;
                float4 g4 = *(const float4*)&lng[c];
                float4 b4 = *(const float4*)&lnb[c];
                float4 ov = make_float4((v.x - mu) * rstd * g4.x + b4.x,
                                        (v.y - mu) * rstd * g4.y + b4.y,
                                        (v.z - mu) * rstd * g4.z + b4.z,
                                        (v.w - mu) * rstd * g4.w + b4.w);
                *(float4*)&OUT[(size_t)gr * ND + c] = ov;
            }
        }
    }
}

// ---------------------------------------------------------------------------
extern "C" void kernel_launch(void* const* d_in, const int* in_sizes, int n_in,
                              void* d_out, int out_size, void* d_ws, size_t ws_size,
                              hipStream_t stream)
{
    const float* F    = (const float*)d_in[0];
    const float* X    = (const float*)d_in[1];
    const float* NUV  = (const float*)d_in[2];
    const int*   TOPK = (const int*)d_in[3];
    const float* qW1  = (const float*)d_in[4];
    const float* qb1  = (const float*)d_in[5];
    const float* qW2  = (const float*)d_in[6];
    const float* qb2  = (const float*)d_in[7];
    const float* gW1  = (const float*)d_in[8];
    const float* gb1  = (const float*)d_in[9];
    const float* gW2  = (const float*)d_in[10];
    const float* gb2  = (const float*)d_in[11];
    const float* kW1  = (const float*)d_in[12];
    const float* kb1  = (const float*)d_in[13];
    const float* kW2  = (const float*)d_in[14];
    const float* kb2  = (const float*)d_in[15];
    const float* vW1  = (const float*)d_in[16];
    const float* vb1  = (const float*)d_in[17];
    const float* vW2  = (const float*)d_in[18];
    const float* vb2  = (const float*)d_in[19];
    const float* dW1  = (const float*)d_in[20];
    const float* db1  = (const float*)d_in[21];
    const float* dW2  = (const float*)d_in[22];
    const float* db2  = (const float*)d_in[23];
    const float* lng  = (const float*)d_in[24];
    const float* lnb  = (const float*)d_in[25];

    const int n = in_sizes[0] / ND;
    char* wsb = (char*)d_ws;

    PrepDesc pd;
    const float* srcs[10] = {qW1, qW2, gW1, gW2, kW1, kW2, vW1, vW2, dW1, dW2};
    u64 offs[10] = {OFF_QW1T, OFF_QW2T, OFF_GW1T, OFF_GW2T, OFF_KW1T,
                    OFF_KW2T, OFF_VW1T, OFF_VW2T, OFF_DW1T, OFF_DW2T};
    int Ns[10]   = {128, 1024, 128, 128, 128, 128, 128, 128, 128, 128};
    int Ksrc[10] = {128, 128, 12, 128, 128, 128, 128, 128, 1024, 128};
    int Kdst[10] = {128, 128, 32, 128, 128, 128, 128, 128, 1024, 128};
    for (int i = 0; i < 10; i++){
        pd.src[i] = srcs[i]; pd.dstoff[i] = offs[i];
        pd.N[i] = Ns[i]; pd.Ksrc[i] = Ksrc[i]; pd.Kdst[i] = Kdst[i];
    }
    prep_weights<<<186, 256, 0, stream>>>(pd, wsb);

    u16* Qg  = (u16*)(wsb + OFF_Q);
    u16* ATT = (u16*)(wsb + OFF_ATT);
    const int nb = (n + 127) / 128;
    const int ngroups = n / 4;

    qmlp_kernel<<<nb, 512, 0, stream>>>(F, qb1, qb2, wsb, Qg, n);
    attn_kernel<<<512, 256, 0, stream>>>(F, X, NUV, TOPK, gb1, gb2,
                                         kb1, kb2, vb1, vb2, wsb, Qg, ATT, ngroups);
    decode_kernel<<<nb, 512, 0, stream>>>(ATT, db1, db2, F, lng, lnb, wsb, (float*)d_out, n);
}

// Round 18
// 382.104 us; speedup vs baseline: 1.0668x; 1.0282x over previous
//
#include <hip/hip_runtime.h>
#include <math.h>
#include <stdint.h>

#define ND 128
#define NNB 32
#define NH 8

typedef __attribute__((ext_vector_type(8))) short bf16x8;
typedef __attribute__((ext_vector_type(4))) float f32x4;
typedef __attribute__((ext_vector_type(8))) unsigned short u16x8;
typedef __attribute__((ext_vector_type(2))) unsigned int u32x2;
typedef unsigned short u16;
typedef unsigned int u32;
typedef unsigned long long u64;

// ---- ws layout (bytes); all weights transposed Wt[N][K] bf16, LINEAR ----
#define OFF_QW1T 0ULL
#define OFF_QW2T 32768ULL
#define OFF_GW1T 294912ULL     // [128][32] (K padded 12->32 with zeros)
#define OFF_GW2T 303104ULL
#define OFF_KW1T 335872ULL
#define OFF_KW2T 368640ULL
#define OFF_VW1T 401408ULL
#define OFF_VW2T 434176ULL
#define OFF_DW1T 466944ULL     // [128][1024]
#define OFF_DW2T 729088ULL
#define OFF_Q    761856ULL     // [20096][1024] bf16, linear
#define OFF_ATT  (OFF_Q + 20096ULL * 2048ULL)  // chunk-swizzled by (pid&7)

// soft barrier: drain LDS ops only (NOT vmcnt) then barrier.
#define SBAR() asm volatile("s_waitcnt lgkmcnt(0)\n\ts_barrier" ::: "memory")

__device__ __forceinline__ u16 rneb(float f){
    u32 u = __builtin_bit_cast(u32, f);
    u32 r = u + 0x7fffu + ((u >> 16) & 1u);
    return (u16)(r >> 16);
}
__device__ __forceinline__ float elu_f(float v){ return v > 0.f ? v : (__expf(v) - 1.f); }

__device__ __forceinline__ u32 cvtpk(float a, float b){
    u32 r;
    asm("v_cvt_pk_bf16_f32 %0, %1, %2" : "=v"(r) : "v"(a), "v"(b));
    return r;
}
__device__ __forceinline__ u32x2 cvt4(float a, float b, float c, float d){
    u32x2 r; r.x = cvtpk(a, b); r.y = cvtpk(c, d); return r;
}

// async global->LDS, 16B per lane (linear dest)
#define GLDS16(g, l) __builtin_amdgcn_global_load_lds( \
    (const __attribute__((address_space(1))) u32*)(g), \
    (__attribute__((address_space(3))) u32*)(u32)(u64)(l), 16, 0, 0)

// fragment read from LDS: row-major [*][128] bf16 (256B rows), byte ^= (r&7)<<4
__device__ __forceinline__ bf16x8 ldfrag(const u16* base, int row, int kb, int l){
    int r = row + (l & 15);
    int byte = (r << 8) + (((kb << 1) + ((l >> 4) << 4)) ^ ((r & 7) << 4));
    return *(const bf16x8*)((const char*)base + byte);
}
// 64B-row variant (RL tile [128][32]), byte ^= (r&3)<<4
__device__ __forceinline__ bf16x8 ldfragRL(const u16* base, int row, int l){
    int r = row + (l & 15);
    int byte = (r << 6) + ((((l >> 4) << 4)) ^ ((r & 3) << 4));
    return *(const bf16x8*)((const char*)base + byte);
}
// fragment directly from global Wt[N][K] (linear, row stride kstride bytes)
__device__ __forceinline__ bf16x8 ldfragG(const char* __restrict__ Wt, int n, int kstride, int kb, int l){
    return *(const bf16x8*)(Wt + (size_t)(n + (l & 15)) * (size_t)kstride
                               + (size_t)((kb << 1) + ((l >> 4) << 4)));
}

// gemm over one row-half (64 rows) with REGISTER-RESIDENT weights.
// wave tile: 32 out-ch (m0) x 64 rows. 16 ds_reads, 32 MFMA.
__device__ __forceinline__ void gemm_half(const bf16x8 aw[4][2], const u16* B,
                                          int nbase, f32x4 acc[2][4], int l){
    __builtin_amdgcn_s_setprio(1);
    #pragma unroll
    for (int kk = 0; kk < 4; kk++){
        #pragma unroll
        for (int nt = 0; nt < 4; nt++){
            bf16x8 b = ldfrag(B, nbase + nt * 16, kk * 32, l);
            acc[0][nt] = __builtin_amdgcn_mfma_f32_16x16x32_bf16(aw[kk][0], b, acc[0][nt], 0, 0, 0);
            acc[1][nt] = __builtin_amdgcn_mfma_f32_16x16x32_bf16(aw[kk][1], b, acc[1][nt], 0, 0, 0);
        }
    }
    __builtin_amdgcn_s_setprio(0);
}

__device__ __forceinline__ void bias_init2(f32x4 acc[2][4], const float* __restrict__ bias,
                                           int m0, int hi){
    #pragma unroll
    for (int mt = 0; mt < 2; mt++){
        float4 bq = *(const float4*)&bias[m0 + mt * 16 + (hi << 2)];
        #pragma unroll
        for (int nt = 0; nt < 4; nt++)
            acc[mt][nt] = (f32x4){bq.x, bq.y, bq.z, bq.w};
    }
}

// full layer, register-weights: ACT 0 linear, 1 elu, 2 linear*dis*F_nn
template<int ACT, bool INPLACE>
__device__ __forceinline__ void layerP(
    const u16* inB, u16* outB, const bf16x8 aw[4][2],
    const float* __restrict__ bias, const float* __restrict__ F,
    const int* sidx, const float* sdis, int m0, int l, int hi)
{
    #pragma unroll
    for (int half = 0; half < 2; half++){
        const int nbase = half * 64;
        float4 fv[2][4]; float ds[4];
        if (ACT == 2){
            #pragma unroll
            for (int nt = 0; nt < 4; nt++){
                int row = nbase + nt * 16 + (l & 15);
                int ix = sidx[row];
                ds[nt] = sdis[row];
                fv[0][nt] = *(const float4*)&F[(size_t)ix * ND + m0 + (hi << 2)];
                fv[1][nt] = *(const float4*)&F[(size_t)ix * ND + m0 + 16 + (hi << 2)];
            }
        }
        f32x4 acc[2][4];
        bias_init2(acc, bias, m0, hi);
        gemm_half(aw, inB, nbase, acc, l);
        if (INPLACE) SBAR();   // all waves' reads of this half done before writes
        #pragma unroll
        for (int mt = 0; mt < 2; mt++){
            int ch0 = m0 + mt * 16 + (hi << 2);
            #pragma unroll
            for (int nt = 0; nt < 4; nt++){
                int row = nbase + nt * 16 + (l & 15);
                float v0 = acc[mt][nt][0], v1 = acc[mt][nt][1];
                float v2 = acc[mt][nt][2], v3 = acc[mt][nt][3];
                if (ACT == 1){ v0 = elu_f(v0); v1 = elu_f(v1); v2 = elu_f(v2); v3 = elu_f(v3); }
                if (ACT == 2){
                    float s = ds[nt];
                    v0 *= s * fv[mt][nt].x; v1 *= s * fv[mt][nt].y;
                    v2 *= s * fv[mt][nt].z; v3 *= s * fv[mt][nt].w;
                }
                *(u32x2*)((char*)outB + (row << 8) + (((ch0 << 1)) ^ ((row & 7) << 4))) =
                    cvt4(v0, v1, v2, v3);
            }
        }
    }
    SBAR();
}

// ---------------------------------------------------------------------------
// prep: W (Ksrc x N f32) -> Wt (N x Kdst bf16, zero-padded), linear
// ---------------------------------------------------------------------------
struct PrepDesc {
    const float* src[10];
    u64 dstoff[10];
    int N[10], Ksrc[10], Kdst[10];
};

__global__ __launch_bounds__(256) void prep_weights(PrepDesc d, char* ws){
    int tid = blockIdx.x * 256 + threadIdx.x;
    #pragma unroll 1
    for (int m = 0; m < 10; m++){
        int cnt = (d.Kdst[m] * d.N[m]) >> 3;
        if (tid < cnt){
            int N = d.N[m];
            int nn = tid % N, k8 = tid / N;
            const float* s = d.src[m];
            u16x8 pk;
            #pragma unroll
            for (int i = 0; i < 8; i++){
                int k = k8 * 8 + i;
                pk[i] = (k < d.Ksrc[m]) ? rneb(s[(size_t)k * N + nn]) : (u16)0;
            }
            *(u16x8*)(ws + d.dstoff[m] + (u64)nn * (u64)(d.Kdst[m] * 2) + (u64)(k8 * 16)) = pk;
            return;
        }
        tid -= cnt;
    }
}

// ---------------------------------------------------------------------------
// qmlp: Q = elu(F@qW1+qb1)@qW2+qb2 -> bf16 LINEAR Q ; 64 rows, 256 thr
// (re-gridded: 313 blocks fills all 256 CUs; wave code identical, n0==0)
// ---------------------------------------------------------------------------
__device__ __forceinline__ void gemm2x4G(const char* __restrict__ Wt, int kstride, int kbase,
                                         const u16* B, f32x4 acc[2][4], int m0, int n0, int l){
    bf16x8 aw[4][2];
    #pragma unroll
    for (int kk = 0; kk < 4; kk++)
        #pragma unroll
        for (int i = 0; i < 2; i++)
            aw[kk][i] = ldfragG(Wt, m0 + i * 16, kstride, kbase + kk * 32, l);
    __builtin_amdgcn_s_setprio(1);
    #pragma unroll
    for (int kk = 0; kk < 4; kk++){
        #pragma unroll
        for (int nt = 0; nt < 4; nt++){
            bf16x8 b = ldfrag(B, n0 + nt * 16, kk * 32, l);
            #pragma unroll
            for (int mt = 0; mt < 2; mt++)
                acc[mt][nt] = __builtin_amdgcn_mfma_f32_16x16x32_bf16(aw[kk][mt], b, acc[mt][nt], 0, 0, 0);
        }
    }
    __builtin_amdgcn_s_setprio(0);
}

__global__ __launch_bounds__(256, 2) void qmlp_kernel(
    const float* __restrict__ F, const float* __restrict__ qb1, const float* __restrict__ qb2,
    const char* __restrict__ ws, u16* __restrict__ Qg, int n)
{
    __shared__ __align__(16) u16 sIn[8192];   // [64][128]
    __shared__ __align__(16) u16 sH[8192];
    const int t = threadIdx.x;
    const int row0 = blockIdx.x * 64;
    const int l = t & 63, w = t >> 6;          // w in 0..3
    const int m0 = (w & 3) * 32, n0 = (w >> 2) * 64;   // n0 == 0
    const int hi = l >> 4;

    for (int i = t; i < 2048; i += 256){
        int r = i >> 5, c = (i & 31) * 4;     // r in 0..63
        int gr = row0 + r;
        float4 v = make_float4(0.f, 0.f, 0.f, 0.f);
        if (gr < n) v = *(const float4*)&F[(size_t)gr * ND + c];
        *(u32x2*)((char*)sIn + (r << 8) + (((c << 1)) ^ ((r & 7) << 4))) = cvt4(v.x, v.y, v.z, v.w);
    }
    SBAR();

    {
        f32x4 acc[2][4];
        bias_init2(acc, qb1, m0, hi);
        gemm2x4G(ws + OFF_QW1T, 256, 0, sIn, acc, m0, n0, l);
        #pragma unroll
        for (int mt = 0; mt < 2; mt++){
            int ch0 = m0 + mt * 16 + (hi << 2);
            #pragma unroll
            for (int nt = 0; nt < 4; nt++){
                int row = n0 + nt * 16 + (l & 15);
                *(u32x2*)((char*)sH + (row << 8) + (((ch0 << 1)) ^ ((row & 7) << 4))) =
                    cvt4(elu_f(acc[mt][nt][0]), elu_f(acc[mt][nt][1]),
                         elu_f(acc[mt][nt][2]), elu_f(acc[mt][nt][3]));
            }
        }
    }
    SBAR();

    for (int ct = 0; ct < 8; ct++){
        f32x4 a2[2][4];
        bias_init2(a2, qb2 + ct * 128, m0, hi);
        gemm2x4G(ws + OFF_QW2T + (u64)ct * 32768ULL, 256, 0, sH, a2, m0, n0, l);
        #pragma unroll
        for (int mt = 0; mt < 2; mt++){
            int ch0 = m0 + mt * 16 + (hi << 2);
            #pragma unroll
            for (int nt = 0; nt < 4; nt++){
                int row = n0 + nt * 16 + (l & 15);
                int gr = row0 + row;
                if (gr < n)
                    *(u64*)((char*)Qg + (size_t)gr * 2048 + (size_t)((ct * 128 + ch0) * 2)) =
                        __builtin_bit_cast(u64, cvt4(a2[mt][nt][0], a2[mt][nt][1],
                                                     a2[mt][nt][2], a2[mt][nt][3]));
            }
        }
    }
}

// ---------------------------------------------------------------------------
// attn: PERSISTENT blocks, weights in VGPRs; 4 pts/group, 256 thr, 4 waves
// (byte-identical to the 392.2us R15 kernel)
// ---------------------------------------------------------------------------
__global__ __launch_bounds__(256, 2)
__attribute__((amdgpu_waves_per_eu(2, 2)))
void attn_kernel(
    const float* __restrict__ F, const float* __restrict__ X,
    const float* __restrict__ NUV, const int* __restrict__ TOPK,
    const float* __restrict__ gb1, const float* __restrict__ gb2,
    const float* __restrict__ kb1, const float* __restrict__ kb2,
    const float* __restrict__ vb1, const float* __restrict__ vb2,
    const char* __restrict__ ws, const u16* __restrict__ Qg, u16* __restrict__ ATT,
    int ngroups)
{
    __shared__ __align__(16) u16 bufA[16384];  // [128][128]
    __shared__ __align__(16) u16 bufB[16384];  // [128][128] (RL [128][32] at group start)
    __shared__ __align__(16) u16 sP16[2048];   // 4 pts x [16 h][32 k] (64B rows, keyed)
    __shared__ float sdis[128];
    __shared__ int   sidx[128];

    const int t = threadIdx.x;
    const int l = t & 63, w = t >> 6;
    const int m0 = w * 32;          // this wave's 32-channel slice
    const int hi = l >> 4;

    // ---- load ALL weights into registers once (persist across group loop) ----
    bf16x8 ag[2];                   // gW1t [128][32]: 64B rows
    #pragma unroll
    for (int i = 0; i < 2; i++)
        ag[i] = *(const bf16x8*)(ws + OFF_GW1T
                 + (u64)((m0 + i * 16 + (l & 15)) * 64 + (hi << 4)));
    bf16x8 wg2[4][2], wk1[4][2], wk2[4][2], wv1[4][2], wv2[4][2];
    #pragma unroll
    for (int kk = 0; kk < 4; kk++)
        #pragma unroll
        for (int i = 0; i < 2; i++){
            u64 fo = (u64)((m0 + i * 16 + (l & 15)) * 256 + kk * 64 + (hi << 4));
            wg2[kk][i] = *(const bf16x8*)(ws + OFF_GW2T + fo);
            wk1[kk][i] = *(const bf16x8*)(ws + OFF_KW1T + fo);
            wk2[kk][i] = *(const bf16x8*)(ws + OFF_KW2T + fo);
            wv1[kk][i] = *(const bf16x8*)(ws + OFF_VW1T + fo);
            wv2[kk][i] = *(const bf16x8*)(ws + OFF_VW2T + fo);
        }

    for (int g = blockIdx.x; g < ngroups; g += gridDim.x){
        const int pid0 = g * 4;
        SBAR();   // previous group's PV reads of bufB done before geometry writes

        // geometry: RL -> bufB [128][32], dis, idx
        if (t < 128){
            int p = t >> 5, k = t & 31;
            int pid = pid0 + p;
            int idx = TOPK[(size_t)pid * NNB + k];
            sidx[t] = idx;
            float x0 = X[(size_t)pid * 3 + 0], x1 = X[(size_t)pid * 3 + 1], x2 = X[(size_t)pid * 3 + 2];
            float ox = X[(size_t)idx * 3 + 0] - x0;
            float oy = X[(size_t)idx * 3 + 1] - x1;
            float oz = X[(size_t)idx * 3 + 2] - x2;
            sdis[t] = __expf(-0.5f * (ox * ox + oy * oy + oz * oz));
            float nv[9];
            #pragma unroll
            for (int i = 0; i < 9; i++) nv[i] = NUV[(size_t)pid * 9 + i];
            float f[12];
            #pragma unroll
            for (int i = 0; i < 3; i++)
                f[i] = nv[i * 3 + 0] * ox + nv[i * 3 + 1] * oy + nv[i * 3 + 2] * oz;
            #pragma unroll
            for (int r = 0; r < 3; r++){
                float a0 = NUV[(size_t)idx * 9 + r * 3 + 0];
                float a1 = NUV[(size_t)idx * 9 + r * 3 + 1];
                float a2 = NUV[(size_t)idx * 9 + r * 3 + 2];
                #pragma unroll
                for (int i = 0; i < 3; i++)
                    f[3 + r * 3 + i] = nv[i * 3 + 0] * a0 + nv[i * 3 + 1] * a1 + nv[i * 3 + 2] * a2;
            }
            char* rb = (char*)bufB + (t << 6);
            u32 key = (u32)(t & 3) << 4;
            *(u32x2*)(rb + (0u ^ key))  = cvt4(f[0], f[1], f[2], f[3]);
            *(u32x2*)(rb + (8u ^ key))  = cvt4(f[4], f[5], f[6], f[7]);
            *(u32x2*)(rb + (16u ^ key)) = cvt4(f[8], f[9], f[10], f[11]);
            *(u32x2*)(rb + (24u ^ key)) = (u32x2){0u, 0u};
            *(u32x2*)(rb + (32u ^ key)) = (u32x2){0u, 0u};
            *(u32x2*)(rb + (40u ^ key)) = (u32x2){0u, 0u};
            *(u32x2*)(rb + (48u ^ key)) = (u32x2){0u, 0u};
            *(u32x2*)(rb + (56u ^ key)) = (u32x2){0u, 0u};
        }
        SBAR();

        // geo L1 (K=32): bufB(RL) -> bufA, elu
        #pragma unroll
        for (int half = 0; half < 2; half++){
            f32x4 acc[2][4];
            bias_init2(acc, gb1, m0, hi);
            __builtin_amdgcn_s_setprio(1);
            #pragma unroll
            for (int nt = 0; nt < 4; nt++){
                bf16x8 bg = ldfragRL(bufB, half * 64 + nt * 16, l);
                acc[0][nt] = __builtin_amdgcn_mfma_f32_16x16x32_bf16(ag[0], bg, acc[0][nt], 0, 0, 0);
                acc[1][nt] = __builtin_amdgcn_mfma_f32_16x16x32_bf16(ag[1], bg, acc[1][nt], 0, 0, 0);
            }
            __builtin_amdgcn_s_setprio(0);
            #pragma unroll
            for (int mt = 0; mt < 2; mt++){
                int ch0 = m0 + mt * 16 + (hi << 2);
                #pragma unroll
                for (int nt = 0; nt < 4; nt++){
                    int row = half * 64 + nt * 16 + (l & 15);
                    *(u32x2*)((char*)bufA + (row << 8) + (((ch0 << 1)) ^ ((row & 7) << 4))) =
                        cvt4(elu_f(acc[mt][nt][0]), elu_f(acc[mt][nt][1]),
                             elu_f(acc[mt][nt][2]), elu_f(acc[mt][nt][3]));
                }
            }
        }
        SBAR();

        layerP<2, false>(bufA, bufB, wg2, gb2, F, sidx, sdis, m0, l, hi); // geo L2 -> G(bufB)
        layerP<1, false>(bufB, bufA, wk1, kb1, F, sidx, sdis, m0, l, hi); // K1 -> bufA
        layerP<0, true >(bufA, bufA, wk2, kb2, F, sidx, sdis, m0, l, hi); // K2 in-place -> K

        // QK + softmax: wave w = point w
        {
            f32x4 s0, s1;
            s0 = 0.f; s1 = 0.f;
            const char* qb = (const char*)Qg + (size_t)(pid0 + w) * 2048
                           + (size_t)(l & 7) * 256 + (size_t)(hi << 4);
            #pragma unroll
            for (int kk = 0; kk < 4; kk++){
                bf16x8 bq = *(const bf16x8*)(qb + kk * 64);
                bf16x8 a0 = ldfrag(bufA, w * 32,      kk * 32, l);
                bf16x8 a1 = ldfrag(bufA, w * 32 + 16, kk * 32, l);
                s0 = __builtin_amdgcn_mfma_f32_16x16x32_bf16(a0, bq, s0, 0, 0, 0);
                s1 = __builtin_amdgcn_mfma_f32_16x16x32_bf16(a1, bq, s1, 0, 0, 0);
            }
            const float RS = 0.08838834764831845f;
            float sv[8];
            #pragma unroll
            for (int mt = 0; mt < 2; mt++)
                #pragma unroll
                for (int j = 0; j < 4; j++){
                    int kidx = mt * 16 + (hi << 2) + j;
                    float x = (mt ? s1[j] : s0[j]) * RS;
                    if (sidx[w * 32 + kidx] == 0) x = -INFINITY;
                    sv[mt * 4 + j] = x;
                }
            float mx = sv[0];
            #pragma unroll
            for (int i = 1; i < 8; i++) mx = fmaxf(mx, sv[i]);
            mx = fmaxf(mx, __shfl_xor(mx, 16));
            mx = fmaxf(mx, __shfl_xor(mx, 32));
            float e[8], sum = 0.f;
            #pragma unroll
            for (int i = 0; i < 8; i++){ e[i] = __expf(sv[i] - mx); sum += e[i]; }
            sum += __shfl_xor(sum, 16);
            sum += __shfl_xor(sum, 32);
            float inv = 1.f / sum;
            int h = l & 15;
            u32 key = (u32)(h & 3) << 4;
            char* pb = (char*)sP16 + w * 1024 + h * 64;
            *(u32x2*)(pb + (((u32)(hi * 8)) ^ key)) =
                cvt4(e[0] * inv, e[1] * inv, e[2] * inv, e[3] * inv);
            *(u32x2*)(pb + (((u32)(32 + hi * 8)) ^ key)) =
                cvt4(e[4] * inv, e[5] * inv, e[6] * inv, e[7] * inv);
        }
        SBAR();

        layerP<1, false>(bufB, bufA, wv1, vb1, F, sidx, sdis, m0, l, hi); // V1 -> Hv(bufA)

        // V2: A = Hv rows(bufA), B = wv2 (registers) -> V^T in bufB [128 ch][128 kv]
        #pragma unroll
        for (int half = 0; half < 2; half++){
            f32x4 a2[4][2];
            #pragma unroll
            for (int ntc = 0; ntc < 2; ntc++){
                float bv = vb2[m0 + ntc * 16 + (l & 15)];
                #pragma unroll
                for (int mtr = 0; mtr < 4; mtr++)
                    a2[mtr][ntc] = (f32x4){bv, bv, bv, bv};
            }
            __builtin_amdgcn_s_setprio(1);
            #pragma unroll
            for (int kk = 0; kk < 4; kk++){
                #pragma unroll
                for (int mtr = 0; mtr < 4; mtr++){
                    bf16x8 a = ldfrag(bufA, half * 64 + mtr * 16, kk * 32, l);
                    #pragma unroll
                    for (int ntc = 0; ntc < 2; ntc++)
                        a2[mtr][ntc] = __builtin_amdgcn_mfma_f32_16x16x32_bf16(a, wv2[kk][ntc], a2[mtr][ntc], 0, 0, 0);
                }
            }
            __builtin_amdgcn_s_setprio(0);
            #pragma unroll
            for (int mtr = 0; mtr < 4; mtr++){
                int kv0 = half * 64 + mtr * 16 + (hi << 2);
                #pragma unroll
                for (int ntc = 0; ntc < 2; ntc++){
                    int ch = m0 + ntc * 16 + (l & 15);
                    *(u32x2*)((char*)bufB + (ch << 8) + (((kv0 << 1)) ^ ((ch & 7) << 4))) =
                        cvt4(a2[mtr][ntc][0], a2[mtr][ntc][1], a2[mtr][ntc][2], a2[mtr][ntc][3]);
                }
            }
        }
        SBAR();

        // PV: O^T = V^T(A) @ P^T(B) ; wave w = point w, full 128 ch
        {
            int pid = pid0 + w;
            int h = l & 15;
            bf16x8 pb = *(const bf16x8*)((const char*)sP16 + w * 1024 + h * 64
                                         + (((u32)(hi * 16)) ^ ((u32)(h & 3) << 4)));
            u32 key = ((u32)pid & 7) << 4;
            char* dst = (char*)ATT + (size_t)pid * 2048;
            #pragma unroll
            for (int nt = 0; nt < 8; nt++){
                f32x4 o;
                o = 0.f;
                bf16x8 av = ldfrag(bufB, nt * 16, w * 32, l);
                o = __builtin_amdgcn_mfma_f32_16x16x32_bf16(av, pb, o, 0, 0, 0);
                if (h < 8){
                    u32 dbyte = (u32)(nt * 32 + hi * 8);
                    *(u32x2*)(dst + h * 256 + (dbyte ^ key)) = cvt4(o[0], o[1], o[2], o[3]);
                }
            }
        }
    }
}

// ---------------------------------------------------------------------------
// decode: out = LN( elu(ATT@dW1+db1)@dW2+db2 + F ) * g + b ; 64 rows, 256 thr
// (re-gridded: 313 blocks fills all 256 CUs)
// ---------------------------------------------------------------------------
__global__ __launch_bounds__(256, 2) void decode_kernel(
    const u16* __restrict__ ATT,
    const float* __restrict__ db1, const float* __restrict__ db2,
    const float* __restrict__ F,
    const float* __restrict__ lng, const float* __restrict__ lnb,
    const char* __restrict__ ws, float* __restrict__ OUT, int n)
{
    __shared__ __align__(16) char SM[33792];
    u16* sA = (u16*)SM;              // [64][128] bf16 (staged from ATT, pre-swizzled)
    u16* sH = (u16*)(SM + 16384);
    float* sO = (float*)SM;          // [64][132] f32 (aliases sA/sH after L2)

    const int t = threadIdx.x;
    const int row0 = blockIdx.x * 64;
    const int l = t & 63, w = t >> 6;          // w in 0..3
    const int m0 = (w & 3) * 32, n0 = (w >> 2) * 64;   // n0 == 0
    const int hi = l >> 4;

    f32x4 acc[2][4];
    bias_init2(acc, db1, m0, hi);
    for (int kc = 0; kc < 8; kc++){
        {
            const int seg = (t & 15) * 16, rr = t >> 4;   // rr in 0..15
            const char* g = (const char*)ATT + (size_t)row0 * 2048 + kc * 256;
            #pragma unroll
            for (int i = 0; i < 4; i++){
                int row = i * 16 + rr;                    // rows 0..63
                GLDS16(g + (size_t)row * 2048 + seg, (char*)sA + row * 256 + seg);
            }
        }
        __syncthreads();
        gemm2x4G(ws + OFF_DW1T, 2048, kc * 128, sA, acc, m0, n0, l);
        SBAR();
    }
    #pragma unroll
    for (int mt = 0; mt < 2; mt++){
        int ch0 = m0 + mt * 16 + (hi << 2);
        #pragma unroll
        for (int nt = 0; nt < 4; nt++){
            int row = n0 + nt * 16 + (l & 15);
            *(u32x2*)((char*)sH + (row << 8) + (((ch0 << 1)) ^ ((row & 7) << 4))) =
                cvt4(elu_f(acc[mt][nt][0]), elu_f(acc[mt][nt][1]),
                     elu_f(acc[mt][nt][2]), elu_f(acc[mt][nt][3]));
        }
    }
    SBAR();

    f32x4 a2[2][4];
    bias_init2(a2, db2, m0, hi);
    gemm2x4G(ws + OFF_DW2T, 256, 0, sH, a2, m0, n0, l);
    SBAR();   // sA/sH dead; sO may alias

    #pragma unroll
    for (int mt = 0; mt < 2; mt++){
        int ch0 = m0 + mt * 16 + (hi << 2);
        #pragma unroll
        for (int nt = 0; nt < 4; nt++){
            int row = n0 + nt * 16 + (l & 15);
            int gr = row0 + row;
            float4 fres = make_float4(0.f, 0.f, 0.f, 0.f);
            if (gr < n) fres = *(const float4*)&F[(size_t)gr * ND + ch0];
            float4 ov = make_float4(a2[mt][nt][0] + fres.x, a2[mt][nt][1] + fres.y,
                                    a2[mt][nt][2] + fres.z, a2[mt][nt][3] + fres.w);
            *(float4*)&sO[row * 132 + ch0] = ov;
        }
    }
    SBAR();

    // LayerNorm: 4 threads per row (32 cols each); r in 0..63
    {
        int r = t >> 2, q = t & 3;
        const float* rowp = sO + r * 132 + q * 32;
        float s = 0.f;
        #pragma unroll
        for (int i = 0; i < 8; i++){
            float4 v = ((const float4*)rowp)[i];
            s += v.x + v.y + v.z + v.w;
        }
        s += __shfl_xor(s, 1);
        s += __shfl_xor(s, 2);
        float mu = s * (1.0f / 128.0f);
        float q2 = 0.f;
        #pragma unroll
        for (int i = 0; i < 8; i++){
            float4 v = ((const float4*)rowp)[i];
            q2 += (v.x - mu) * (v.x - mu) + (v.y - mu) * (v.y - mu)
                + (v.z - mu) * (v.z - mu) + (v.w - mu) * (v.w - mu);
        }
        q2 += __shfl_xor(q2, 1);
        q2 += __shfl_xor(q2, 2);
        float rstd = rsqrtf(q2 * (1.0f / 128.0f) + 1e-5f);
        int gr = row0 + r;
        if (gr < n){
            #pragma unroll
            for (int i = 0; i < 8; i++){
                float4 v = ((const float4*)rowp)[i];
                int c = q * 32 + i * 4;
                float4 g4 = *(const float4*)&lng[c];
                float4 b4 = *(const float4*)&lnb[c];
                float4 ov = make_float4((v.x - mu) * rstd * g4.x + b4.x,
                                        (v.y - mu) * rstd * g4.y + b4.y,
                                        (v.z - mu) * rstd * g4.z + b4.z,
                                        (v.w - mu) * rstd * g4.w + b4.w);
                *(float4*)&OUT[(size_t)gr * ND + c] = ov;
            }
        }
    }
}

// ---------------------------------------------------------------------------
extern "C" void kernel_launch(void* const* d_in, const int* in_sizes, int n_in,
                              void* d_out, int out_size, void* d_ws, size_t ws_size,
                              hipStream_t stream)
{
    const float* F    = (const float*)d_in[0];
    const float* X    = (const float*)d_in[1];
    const float* NUV  = (const float*)d_in[2];
    const int*   TOPK = (const int*)d_in[3];
    const float* qW1  = (const float*)d_in[4];
    const float* qb1  = (const float*)d_in[5];
    const float* qW2  = (const float*)d_in[6];
    const float* qb2  = (const float*)d_in[7];
    const float* gW1  = (const float*)d_in[8];
    const float* gb1  = (const float*)d_in[9];
    const float* gW2  = (const float*)d_in[10];
    const float* gb2  = (const float*)d_in[11];
    const float* kW1  = (const float*)d_in[12];
    const float* kb1  = (const float*)d_in[13];
    const float* kW2  = (const float*)d_in[14];
    const float* kb2  = (const float*)d_in[15];
    const float* vW1  = (const float*)d_in[16];
    const float* vb1  = (const float*)d_in[17];
    const float* vW2  = (const float*)d_in[18];
    const float* vb2  = (const float*)d_in[19];
    const float* dW1  = (const float*)d_in[20];
    const float* db1  = (const float*)d_in[21];
    const float* dW2  = (const float*)d_in[22];
    const float* db2  = (const float*)d_in[23];
    const float* lng  = (const float*)d_in[24];
    const float* lnb  = (const float*)d_in[25];

    const int n = in_sizes[0] / ND;
    char* wsb = (char*)d_ws;

    PrepDesc pd;
    const float* srcs[10] = {qW1, qW2, gW1, gW2, kW1, kW2, vW1, vW2, dW1, dW2};
    u64 offs[10] = {OFF_QW1T, OFF_QW2T, OFF_GW1T, OFF_GW2T, OFF_KW1T,
                    OFF_KW2T, OFF_VW1T, OFF_VW2T, OFF_DW1T, OFF_DW2T};
    int Ns[10]   = {128, 1024, 128, 128, 128, 128, 128, 128, 128, 128};
    int Ksrc[10] = {128, 128, 12, 128, 128, 128, 128, 128, 1024, 128};
    int Kdst[10] = {128, 128, 32, 128, 128, 128, 128, 128, 1024, 128};
    for (int i = 0; i < 10; i++){
        pd.src[i] = srcs[i]; pd.dstoff[i] = offs[i];
        pd.N[i] = Ns[i]; pd.Ksrc[i] = Ksrc[i]; pd.Kdst[i] = Kdst[i];
    }
    prep_weights<<<186, 256, 0, stream>>>(pd, wsb);

    u16* Qg  = (u16*)(wsb + OFF_Q);
    u16* ATT = (u16*)(wsb + OFF_ATT);
    const int nb = (n + 63) / 64;
    const int ngroups = n / 4;

    qmlp_kernel<<<nb, 256, 0, stream>>>(F, qb1, qb2, wsb, Qg, n);
    attn_kernel<<<512, 256, 0, stream>>>(F, X, NUV, TOPK, gb1, gb2,
                                         kb1, kb2, vb1, vb2, wsb, Qg, ATT, ngroups);
    decode_kernel<<<nb, 256, 0, stream>>>(ATT, db1, db2, F, lng, lnb, wsb, (float*)d_out, n);
}